// Round 17
// baseline (147.364 us; speedup 1.0000x reference)
//
#include <hip/hip_runtime.h>
#include <hip/hip_bf16.h>
#include <cstdint>

// Problem constants (from reference)
#define B_SZ   2
#define L_SEQ  2048
#define HID    4096
#define NH     16
#define NKV    4
#define HD     64
#define NQKV   (NH + 2*NKV)      // 24
#define QKV_N  (NQKV*HD)         // 1536
#define O_N    (NH*HD)           // 1024
#define M_ROWS (B_SZ*L_SEQ)      // 4096
#define EPSV   1e-6f

typedef __bf16  bf16x8_t  __attribute__((ext_vector_type(8)));
typedef float   f32x4_t   __attribute__((ext_vector_type(4)));
typedef unsigned short ushort8_t __attribute__((ext_vector_type(8)));

__device__ __forceinline__ unsigned short f2b(float f) {
    union { float f; uint32_t u; } v; v.f = f;
    uint32_t r = v.u + 0x7FFFu + ((v.u >> 16) & 1u);   // RNE to bf16
    return (unsigned short)(r >> 16);
}
__device__ __forceinline__ float b2f(unsigned short u) {
    union { uint32_t u; float f; } v; v.u = ((uint32_t)u) << 16;
    return v.f;
}

__device__ __forceinline__ void gload_lds16(const void* g, void* l) {
    __builtin_amdgcn_global_load_lds(
        (__attribute__((address_space(1))) void*)(g),
        (__attribute__((address_space(3))) void*)(l),
        16, 0, 0);
}

#define BARF() do { asm volatile("" ::: "memory"); \
                    __builtin_amdgcn_s_barrier();  \
                    asm volatile("" ::: "memory"); } while (0)
#define LGKMW() asm volatile("s_waitcnt lgkmcnt(0)" ::: "memory")

template <int N> __device__ __forceinline__ void vmcnt_wait() {
    if constexpr (N == 4)       asm volatile("s_waitcnt vmcnt(4)"  ::: "memory");
    else if constexpr (N == 5)  asm volatile("s_waitcnt vmcnt(5)"  ::: "memory");
    else if constexpr (N == 6)  asm volatile("s_waitcnt vmcnt(6)"  ::: "memory");
    else if constexpr (N == 8)  asm volatile("s_waitcnt vmcnt(8)"  ::: "memory");
    else if constexpr (N == 12) asm volatile("s_waitcnt vmcnt(12)" ::: "memory");
    else                        asm volatile("s_waitcnt vmcnt(0)"  ::: "memory");
}

// ===========================================================================
// prep: ONE launch doing (a) hid fp32->bf16 cvt (blocks 0..8191) and
// (b) both weight transposes fp32(RxC) -> bf16(CxR) (blocks 8192..18431).
// ===========================================================================
#define CVT_BLKS 8192            // (M_ROWS*HID/8) / 256
__global__ __launch_bounds__(256) void prep(const float* __restrict__ hid,
                                            unsigned short* __restrict__ Hb,
                                            const float* __restrict__ Wqkv,
                                            unsigned short* __restrict__ WqkvT,
                                            const float* __restrict__ Wo,
                                            unsigned short* __restrict__ WoT) {
    if (blockIdx.x < CVT_BLKS) {
        int i = blockIdx.x * 256 + threadIdx.x;
        const float4* p = (const float4*)(hid + (size_t)i * 8);
        float4 a = p[0], b = p[1];
        ushort8_t o;
        o[0]=f2b(a.x); o[1]=f2b(a.y); o[2]=f2b(a.z); o[3]=f2b(a.w);
        o[4]=f2b(b.x); o[5]=f2b(b.y); o[6]=f2b(b.z); o[7]=f2b(b.w);
        *(ushort8_t*)(Hb + (size_t)i * 8) = o;
        return;
    }
    __shared__ float t[32][33];
    const float* in;
    unsigned short* out;
    int R, C, bx, by;
    int blk = blockIdx.x - CVT_BLKS;
    if (blk < 6144) {
        in = Wqkv; out = WqkvT; R = HID; C = QKV_N;
        bx = blk % 48; by = blk / 48;
    } else {
        blk -= 6144;
        in = Wo; out = WoT; R = O_N; C = HID;
        bx = blk % 128; by = blk / 128;
    }
    const int c0 = bx * 32;
    const int r0 = by * 32;
    const int tx = threadIdx.x & 31;
    const int ty = threadIdx.x >> 5;
    #pragma unroll
    for (int i = 0; i < 32; i += 8)
        t[ty + i][tx] = in[(size_t)(r0 + ty + i) * C + c0 + tx];
    __syncthreads();
    #pragma unroll
    for (int i = 0; i < 32; i += 8)
        out[(size_t)(c0 + ty + i) * R + r0 + tx] = f2b(t[tx][ty + i]);
}

// ===========================================================================
// Single-barrier multi-buffered MFMA GEMM template (round-6 proven; G1 only).
// ===========================================================================
template <int BM, int BN, int BK, int NBUF, int NWM, int NWN, bool OBF16, typename OutT>
__global__ __launch_bounds__(512, 2)
void gemm_sb(const unsigned short* __restrict__ A,
             const unsigned short* __restrict__ Bt,
             OutT* __restrict__ C, int M, int N, int K) {
    constexpr int WM    = BM / NWM;
    constexpr int WN    = BN / NWN;
    constexpr int AF    = WM / 16;
    constexpr int BF    = WN / 16;
    constexpr int KK    = BK / 32;
    constexpr int BUF   = (BM + BN) * BK;
    constexpr int ROWS  = 4096 / BK;
    constexpr int AR    = BM / ROWS;
    constexpr int BR    = BN / ROWS;
    constexpr int RNDS  = AR + BR;
    constexpr int DEPTH = NBUF - 2;

    __shared__ unsigned short smem[NBUF * BUF];

    const int tid  = threadIdx.x;
    const int lane = tid & 63;
    const int wave = tid >> 6;
    const int wm   = wave / NWN;
    const int wn   = wave % NWN;
    const int fr   = lane & 15;
    const int fq   = lane >> 4;

    const int nbx = N / BN;
    int bid = blockIdx.x;
    const int cpx = gridDim.x >> 3;
    bid = (bid & 7) * cpx + (bid >> 3);
    const int bx = bid % nbx, by = bid / nbx;
    const int m0 = by * BM, n0 = bx * BN;

    const int srow = tid / (BK / 8);
    const int sch  = tid & (BK / 8 - 1);
    const int ssw  = (BK == 64) ? (srow & 7) : ((srow >> 1) & 3);
    const int scs  = (sch ^ ssw) << 3;
    const unsigned short* gA = A  + (size_t)(m0 + srow) * K + scs;
    const unsigned short* gB = Bt + (size_t)(n0 + srow) * K + scs;

    const int frsw = (BK == 64) ? (fr & 7) : ((fr >> 1) & 3);

    f32x4_t acc[AF][BF];
    #pragma unroll
    for (int m = 0; m < AF; m++)
        #pragma unroll
        for (int n = 0; n < BF; n++)
            acc[m][n] = (f32x4_t){0.f, 0.f, 0.f, 0.f};

    const int NT = K / BK;

    auto STAGE = [&](int T) {
        const int pb = (T % NBUF) * BUF;
        #pragma unroll
        for (int q = 0; q < AR; ++q)
            gload_lds16(gA + (size_t)(q * ROWS) * K + (size_t)T * BK,
                        &smem[pb + q * 4096 + tid * 8]);
        #pragma unroll
        for (int q = 0; q < BR; ++q)
            gload_lds16(gB + (size_t)(q * ROWS) * K + (size_t)T * BK,
                        &smem[pb + BM * BK + q * 4096 + tid * 8]);
    };

    #pragma unroll
    for (int pt = 0; pt < NBUF - 1; ++pt) STAGE(pt);
    vmcnt_wait<DEPTH * RNDS>();

    for (int t = 0; t < NT; ++t) {
        const int sb = (t % NBUF) * BUF;
        BARF();   // the ONLY barrier per tile

        #pragma unroll
        for (int kk = 0; kk < KK; ++kk) {
            const int cxk = (((kk * 4 + fq) ^ frsw)) << 3;
            bf16x8_t aF[AF], bF[BF];
            #pragma unroll
            for (int mm = 0; mm < AF; ++mm)
                aF[mm] = *(const bf16x8_t*)&smem[sb + (wm*WM + mm*16 + fr)*BK + cxk];
            #pragma unroll
            for (int nn = 0; nn < BF; ++nn)
                bF[nn] = *(const bf16x8_t*)&smem[sb + BM*BK + (wn*WN + nn*16 + fr)*BK + cxk];

            if (kk == 0 && t + NBUF - 1 < NT) STAGE(t + NBUF - 1);

            __builtin_amdgcn_s_setprio(1);
            #pragma unroll
            for (int mm = 0; mm < AF; ++mm)
                #pragma unroll
                for (int nn = 0; nn < BF; ++nn)
                    acc[mm][nn] = __builtin_amdgcn_mfma_f32_16x16x32_bf16(
                        aF[mm], bF[nn], acc[mm][nn], 0, 0, 0);
            __builtin_amdgcn_s_setprio(0);
        }

        if constexpr (DEPTH == 2) {
            if (t + 3 < NT)      { vmcnt_wait<2 * RNDS>(); }
            else if (t + 2 < NT) { vmcnt_wait<RNDS>(); }
            else if (t + 1 < NT) { vmcnt_wait<0>(); }
        } else {
            if (t + 2 < NT)      { vmcnt_wait<RNDS>(); }
            else if (t + 1 < NT) { vmcnt_wait<0>(); }
        }
    }

    // C/D layout (m89-verified): col = lane&15, row = (lane>>4)*4 + reg
    const int crow = m0 + wm * WM + fq * 4;
    const int ccol = n0 + wn * WN + fr;
    #pragma unroll
    for (int m = 0; m < AF; m++)
        #pragma unroll
        for (int n = 0; n < BF; n++)
            #pragma unroll
            for (int rr = 0; rr < 4; rr++) {
                const size_t idx = (size_t)(crow + m*16 + rr) * N + ccol + n*16;
                if constexpr (OBF16) C[idx] = (OutT)f2b(acc[m][n][rr]);
                else                 C[idx] = (OutT)acc[m][n][rr];
            }
}

// ===========================================================================
// GEMM2 (NEW): independent-block TLP variant.
//   out[4096,4096] = attnb @ WoT^T, K=1024.
//   128x128 tile, BK=64, NBUF=2 (64 KB LDS) -> 2 blocks/CU co-resident.
//   256 threads = 4 waves 2Mx2N (per-wave 64x64, AF=BF=4, best intensity).
//   Grid 32x32 = 1024 blocks. Single barrier + vmcnt(0)/tile: the drain is
//   hidden by the OTHER resident block's MFMAs (m97/m114 mechanism), and
//   staging is L2-resident (16MB working set) so latency ~200cy.
//   Epilogue: whole 128x128 fp32 tile through the (exactly 64KB) LDS with
//   float-granular XOR swizzle col^((row&7)<<2); reads lane-stride-4
//   (bank-even), stores 256B-contiguous segments.
// ===========================================================================
__global__ __launch_bounds__(256, 2)
void gemm2_tlp(const unsigned short* __restrict__ A,
               const unsigned short* __restrict__ Bt,
               float* __restrict__ C) {
    constexpr int K   = O_N;         // 1024
    constexpr int N   = HID;         // 4096
    constexpr int NT  = K / 64;      // 16
    constexpr int BUF = 16384;       // shorts per buffer (32 KB): A 128x64 | B 128x64

    __shared__ unsigned short smem[2 * BUF];   // 64 KiB

    const int tid  = threadIdx.x;
    const int lane = tid & 63;
    const int wave = tid >> 6;       // 0..3
    const int wm   = wave >> 1;      // 0..1 (M half, 64 rows)
    const int wn   = wave & 1;       // 0..1 (N half, 64 cols)
    const int fr   = lane & 15;
    const int fq   = lane >> 4;

    const int nbx = N >> 7;          // 32
    int bid = blockIdx.x;
    const int cpx = gridDim.x >> 3;  // 128
    bid = (bid & 7) * cpx + (bid >> 3);
    const int bx = bid % nbx, by = bid / nbx;
    const int m0 = by << 7, n0 = bx << 7;

    // staging: round q covers rows q*32 + (tid>>3); 16B chunk tid&7, swizzled
    const int srow = tid >> 3;
    const int scs  = ((tid & 7) ^ (srow & 7)) << 3;
    const unsigned short* gA = A  + (size_t)(m0 + srow) * K + scs;
    const unsigned short* gB = Bt + (size_t)(n0 + srow) * K + scs;
    const int frsw = fr & 7;

    f32x4_t acc[4][4];
    #pragma unroll
    for (int m = 0; m < 4; m++)
        #pragma unroll
        for (int n = 0; n < 4; n++)
            acc[m][n] = (f32x4_t){0.f, 0.f, 0.f, 0.f};

    auto STAGE = [&](int T) {
        const int pb = (T & 1) * BUF;
        #pragma unroll
        for (int q = 0; q < 4; ++q)
            gload_lds16(gA + (size_t)(q * 32) * K + (size_t)T * 64,
                        &smem[pb + q * 2048 + tid * 8]);
        #pragma unroll
        for (int q = 0; q < 4; ++q)
            gload_lds16(gB + (size_t)(q * 32) * K + (size_t)T * 64,
                        &smem[pb + 8192 + q * 2048 + tid * 8]);
    };

    STAGE(0);
    vmcnt_wait<0>();

    for (int t = 0; t < NT; ++t) {
        const int sb = (t & 1) * BUF;
        BARF();   // the ONLY barrier per tile

        #pragma unroll
        for (int kk = 0; kk < 2; ++kk) {
            const int cxk = (((kk * 4 + fq) ^ frsw)) << 3;
            bf16x8_t aF[4], bF[4];
            #pragma unroll
            for (int mm = 0; mm < 4; ++mm)
                aF[mm] = *(const bf16x8_t*)&smem[sb + (wm*64 + mm*16 + fr)*64 + cxk];
            #pragma unroll
            for (int nn = 0; nn < 4; ++nn)
                bF[nn] = *(const bf16x8_t*)&smem[sb + 8192 + (wn*64 + nn*16 + fr)*64 + cxk];

            if (kk == 0 && t + 1 < NT) STAGE(t + 1);

            __builtin_amdgcn_s_setprio(1);
            #pragma unroll
            for (int mm = 0; mm < 4; ++mm)
                #pragma unroll
                for (int nn = 0; nn < 4; ++nn)
                    acc[mm][nn] = __builtin_amdgcn_mfma_f32_16x16x32_bf16(
                        aF[mm], bF[nn], acc[mm][nn], 0, 0, 0);
            __builtin_amdgcn_s_setprio(0);
        }

        // full drain: tile t+1 landed; hidden by the sibling resident block
        if (t + 1 < NT) vmcnt_wait<0>();
    }

    // ---- coalesced epilogue (whole tile in one pass; LDS = 128x128 fp32)
    float* lf = (float*)smem;
    BARF();   // K-loop LDS reads done everywhere
    #pragma unroll
    for (int m = 0; m < 4; m++)
        #pragma unroll
        for (int n = 0; n < 4; n++)
            #pragma unroll
            for (int rr = 0; rr < 4; rr++) {
                const int row = wm*64 + m*16 + fq*4 + rr;
                const int col = wn*64 + n*16 + fr;
                lf[row*128 + (col ^ ((row & 7) << 2))] = acc[m][n][rr];
            }
    BARF();
    #pragma unroll
    for (int s = 0; s < 8; s++) {
        const int row = s*16 + (tid >> 4);
        const int sw  = (row & 7) << 2;
        const int c0  = (tid & 15) * 4;
        const float4 v0 = *(const float4*)&lf[row*128 + ((c0     ) ^ sw)];
        const float4 v1 = *(const float4*)&lf[row*128 + ((c0 + 64) ^ sw)];
        *(float4*)&C[(size_t)(m0 + row) * N + n0 + c0]      = v0;
        *(float4*)&C[(size_t)(m0 + row) * N + n0 + c0 + 64] = v1;
    }
}

// --------- fused RMSNorm + RoPE + 16-token block-diagonal attention --------
__global__ __launch_bounds__(64) void attn_fused(const unsigned short* __restrict__ qkv,
                                                 const float* __restrict__ cosb,
                                                 const float* __restrict__ sinb,
                                                 const float* __restrict__ qw,
                                                 const float* __restrict__ kw,
                                                 unsigned short* __restrict__ out) {
    const int h    = blockIdx.x & (NH - 1);
    const int blk  = (blockIdx.x >> 4) & 127;
    const int b    = blockIdx.x >> 11;
    const int pos0 = blk * 16;
    const int kvh  = h >> 2;

    const int lane = threadIdx.x;
    const int r    = lane >> 2;
    const int qp   = lane & 3;
    const int d0   = qp * 16;

    __shared__ float qs[16][65];
    __shared__ float ks[16][65];
    __shared__ float vs[16][65];
    __shared__ float ps[16][17];

    const size_t rowb = ((size_t)(b * L_SEQ + pos0 + r)) * NQKV;
    const unsigned short* qptr = qkv + (rowb + h) * HD + d0;
    const unsigned short* kptr = qkv + (rowb + NH + kvh) * HD + d0;
    const unsigned short* vptr = qkv + (rowb + NH + NKV + kvh) * HD + d0;
    const size_t csrow = ((size_t)(b * L_SEQ + pos0 + r)) * HD + d0;

    float q[16], k[16], v[16], cs[16], sn[16];
    {
        ushort8_t q0 = *(const ushort8_t*)&qptr[0], q1 = *(const ushort8_t*)&qptr[8];
        ushort8_t k0 = *(const ushort8_t*)&kptr[0], k1 = *(const ushort8_t*)&kptr[8];
        ushort8_t v0 = *(const ushort8_t*)&vptr[0], v1 = *(const ushort8_t*)&vptr[8];
        #pragma unroll
        for (int i = 0; i < 8; i++) {
            q[i] = b2f(q0[i]); q[i+8] = b2f(q1[i]);
            k[i] = b2f(k0[i]); k[i+8] = b2f(k1[i]);
            v[i] = b2f(v0[i]); v[i+8] = b2f(v1[i]);
        }
        #pragma unroll
        for (int i = 0; i < 16; i += 4) {
            *(float4*)&cs[i] = *(const float4*)&cosb[csrow + i];
            *(float4*)&sn[i] = *(const float4*)&sinb[csrow + i];
        }
    }

    float sq = 0.f, sk = 0.f;
    #pragma unroll
    for (int i = 0; i < 16; i++) { sq += q[i]*q[i]; sk += k[i]*k[i]; }
    sq += __shfl_xor(sq, 1); sq += __shfl_xor(sq, 2);
    sk += __shfl_xor(sk, 1); sk += __shfl_xor(sk, 2);
    const float rq = rsqrtf(sq * (1.f / HD) + EPSV);
    const float rk = rsqrtf(sk * (1.f / HD) + EPSV);

    const float sgn = (qp < 2) ? -1.f : 1.f;
    #pragma unroll
    for (int i = 0; i < 16; i++) {
        float qn = q[i] * rq * qw[d0 + i];
        float kn = k[i] * rk * kw[d0 + i];
        float qo = __shfl_xor(qn, 2);
        float ko = __shfl_xor(kn, 2);
        qs[r][d0 + i] = qn * cs[i] + sgn * qo * sn[i];
        ks[r][d0 + i] = kn * cs[i] + sgn * ko * sn[i];
        vs[r][d0 + i] = v[i];
    }
    __syncthreads();

    float sc[4] = {0.f, 0.f, 0.f, 0.f};
    for (int d = 0; d < 64; d++) {
        const float qd = qs[r][d];
        sc[0] += qd * ks[qp     ][d];
        sc[1] += qd * ks[qp +  4][d];
        sc[2] += qd * ks[qp +  8][d];
        sc[3] += qd * ks[qp + 12][d];
    }
    #pragma unroll
    for (int cc = 0; cc < 4; cc++) {
        const int c = qp + cc * 4;
        sc[cc] = (c <= r) ? sc[cc] * 0.125f : -3.0e38f;
    }
    float mx = fmaxf(fmaxf(sc[0], sc[1]), fmaxf(sc[2], sc[3]));
    mx = fmaxf(mx, __shfl_xor(mx, 1));
    mx = fmaxf(mx, __shfl_xor(mx, 2));
    float e[4], sum = 0.f;
    #pragma unroll
    for (int cc = 0; cc < 4; cc++) { e[cc] = __expf(sc[cc] - mx); sum += e[cc]; }
    sum += __shfl_xor(sum, 1); sum += __shfl_xor(sum, 2);
    const float inv = 1.f / sum;
    #pragma unroll
    for (int cc = 0; cc < 4; cc++) ps[r][qp + cc * 4] = e[cc] * inv;
    __syncthreads();

    float o[16];
    #pragma unroll
    for (int i = 0; i < 16; i++) o[i] = 0.f;
    #pragma unroll
    for (int c = 0; c < 16; c++) {
        const float p = ps[r][c];
        #pragma unroll
        for (int i = 0; i < 16; i++) o[i] += p * vs[c][d0 + i];
    }

    __attribute__((aligned(16))) unsigned short ob[16];
    #pragma unroll
    for (int i = 0; i < 16; i++) ob[i] = f2b(o[i]);
    unsigned short* optr = out + (((size_t)(b * L_SEQ + pos0 + r) * NH + h) * HD) + d0;
    *(uint4*)optr       = *(uint4*)&ob[0];
    *((uint4*)optr + 1) = *(uint4*)&ob[8];
}

// ---------------------------------------------------------------------------
extern "C" void kernel_launch(void* const* d_in, const int* in_sizes, int n_in,
                              void* d_out, int out_size, void* d_ws, size_t ws_size,
                              hipStream_t stream) {
    const float* hid  = (const float*)d_in[0];
    const float* cosb = (const float*)d_in[2];
    const float* sinb = (const float*)d_in[3];
    const float* Wqkv = (const float*)d_in[4];
    const float* Wo   = (const float*)d_in[5];
    const float* qw   = (const float*)d_in[6];
    const float* kw   = (const float*)d_in[7];
    float* outp = (float*)d_out;

    char* ws = (char*)d_ws;
    unsigned short* Hb    = (unsigned short*)ws; ws += (size_t)M_ROWS * HID * 2;
    unsigned short* WqkvT = (unsigned short*)ws; ws += (size_t)QKV_N * HID * 2;
    unsigned short* WoT   = (unsigned short*)ws; ws += (size_t)HID * O_N * 2;
    unsigned short* qkvb  = (unsigned short*)ws; ws += (size_t)M_ROWS * QKV_N * 2;
    unsigned short* attnb = (unsigned short*)ws;

    // prep: cvt + both transposes in ONE launch
    prep<<<dim3(CVT_BLKS + 6144 + 4096), 256, 0, stream>>>
        (hid, Hb, Wqkv, WqkvT, Wo, WoT);

    // GEMM1 (measured best): 128x192, BK=64, NBUF=3, 256 blocks
    gemm_sb<128, 192, 64, 3, 2, 4, true, unsigned short>
        <<<dim3((M_ROWS / 128) * (QKV_N / 192)), 512, 0, stream>>>
        (Hb, WqkvT, qkvb, M_ROWS, QKV_N, HID);

    // fused rmsnorm + rope + block-diag attention (bf16 in/out)
    attn_fused<<<dim3(B_SZ * (L_SEQ / 16) * NH), 64, 0, stream>>>(qkvb, cosb, sinb, qw, kw, attnb);

    // GEMM2 (NEW): 128^2 / NBUF=2 / 256-thread / 2 blocks-per-CU TLP,
    // grid 1024, coalesced epilogue
    gemm2_tlp<<<dim3((M_ROWS / 128) * (HID / 128)), 256, 0, stream>>>
        (attnb, WoT, outp);
}

// Round 18
// 143.283 us; speedup vs baseline: 1.0285x; 1.0285x over previous
//
#include <hip/hip_runtime.h>
#include <hip/hip_bf16.h>
#include <cstdint>

// Problem constants (from reference)
#define B_SZ   2
#define L_SEQ  2048
#define HID    4096
#define NH     16
#define NKV    4
#define HD     64
#define NQKV   (NH + 2*NKV)      // 24
#define QKV_N  (NQKV*HD)         // 1536
#define O_N    (NH*HD)           // 1024
#define M_ROWS (B_SZ*L_SEQ)      // 4096
#define EPSV   1e-6f

typedef __bf16  bf16x8_t  __attribute__((ext_vector_type(8)));
typedef float   f32x4_t   __attribute__((ext_vector_type(4)));
typedef unsigned short ushort8_t __attribute__((ext_vector_type(8)));

__device__ __forceinline__ unsigned short f2b(float f) {
    union { float f; uint32_t u; } v; v.f = f;
    uint32_t r = v.u + 0x7FFFu + ((v.u >> 16) & 1u);   // RNE to bf16
    return (unsigned short)(r >> 16);
}
__device__ __forceinline__ float b2f(unsigned short u) {
    union { uint32_t u; float f; } v; v.u = ((uint32_t)u) << 16;
    return v.f;
}

__device__ __forceinline__ void gload_lds16(const void* g, void* l) {
    __builtin_amdgcn_global_load_lds(
        (__attribute__((address_space(1))) void*)(g),
        (__attribute__((address_space(3))) void*)(l),
        16, 0, 0);
}

#define BARF() do { asm volatile("" ::: "memory"); \
                    __builtin_amdgcn_s_barrier();  \
                    asm volatile("" ::: "memory"); } while (0)
#define LGKMW() asm volatile("s_waitcnt lgkmcnt(0)" ::: "memory")

template <int N> __device__ __forceinline__ void vmcnt_wait() {
    if constexpr (N == 4)       asm volatile("s_waitcnt vmcnt(4)"  ::: "memory");
    else if constexpr (N == 5)  asm volatile("s_waitcnt vmcnt(5)"  ::: "memory");
    else if constexpr (N == 6)  asm volatile("s_waitcnt vmcnt(6)"  ::: "memory");
    else if constexpr (N == 8)  asm volatile("s_waitcnt vmcnt(8)"  ::: "memory");
    else if constexpr (N == 12) asm volatile("s_waitcnt vmcnt(12)" ::: "memory");
    else                        asm volatile("s_waitcnt vmcnt(0)"  ::: "memory");
}

// ===========================================================================
// prep: ONE launch doing (a) hid fp32->bf16 cvt (blocks 0..8191) and
// (b) both weight transposes fp32(RxC) -> bf16(CxR) (blocks 8192..18431).
// ===========================================================================
#define CVT_BLKS 8192            // (M_ROWS*HID/8) / 256
__global__ __launch_bounds__(256) void prep(const float* __restrict__ hid,
                                            unsigned short* __restrict__ Hb,
                                            const float* __restrict__ Wqkv,
                                            unsigned short* __restrict__ WqkvT,
                                            const float* __restrict__ Wo,
                                            unsigned short* __restrict__ WoT) {
    if (blockIdx.x < CVT_BLKS) {
        int i = blockIdx.x * 256 + threadIdx.x;
        const float4* p = (const float4*)(hid + (size_t)i * 8);
        float4 a = p[0], b = p[1];
        ushort8_t o;
        o[0]=f2b(a.x); o[1]=f2b(a.y); o[2]=f2b(a.z); o[3]=f2b(a.w);
        o[4]=f2b(b.x); o[5]=f2b(b.y); o[6]=f2b(b.z); o[7]=f2b(b.w);
        *(ushort8_t*)(Hb + (size_t)i * 8) = o;
        return;
    }
    __shared__ float t[32][33];
    const float* in;
    unsigned short* out;
    int R, C, bx, by;
    int blk = blockIdx.x - CVT_BLKS;
    if (blk < 6144) {
        in = Wqkv; out = WqkvT; R = HID; C = QKV_N;
        bx = blk % 48; by = blk / 48;
    } else {
        blk -= 6144;
        in = Wo; out = WoT; R = O_N; C = HID;
        bx = blk % 128; by = blk / 128;
    }
    const int c0 = bx * 32;
    const int r0 = by * 32;
    const int tx = threadIdx.x & 31;
    const int ty = threadIdx.x >> 5;
    #pragma unroll
    for (int i = 0; i < 32; i += 8)
        t[ty + i][tx] = in[(size_t)(r0 + ty + i) * C + c0 + tx];
    __syncthreads();
    #pragma unroll
    for (int i = 0; i < 32; i += 8)
        out[(size_t)(c0 + ty + i) * R + r0 + tx] = f2b(t[tx][ty + i]);
}

// ===========================================================================
// Single-barrier multi-buffered MFMA GEMM template (round-6 proven; G1).
// ===========================================================================
template <int BM, int BN, int BK, int NBUF, int NWM, int NWN, bool OBF16, typename OutT>
__global__ __launch_bounds__(512, 2)
void gemm_sb(const unsigned short* __restrict__ A,
             const unsigned short* __restrict__ Bt,
             OutT* __restrict__ C, int M, int N, int K) {
    constexpr int WM    = BM / NWM;
    constexpr int WN    = BN / NWN;
    constexpr int AF    = WM / 16;
    constexpr int BF    = WN / 16;
    constexpr int KK    = BK / 32;
    constexpr int BUF   = (BM + BN) * BK;
    constexpr int ROWS  = 4096 / BK;
    constexpr int AR    = BM / ROWS;
    constexpr int BR    = BN / ROWS;
    constexpr int RNDS  = AR + BR;
    constexpr int DEPTH = NBUF - 2;

    __shared__ unsigned short smem[NBUF * BUF];

    const int tid  = threadIdx.x;
    const int lane = tid & 63;
    const int wave = tid >> 6;
    const int wm   = wave / NWN;
    const int wn   = wave % NWN;
    const int fr   = lane & 15;
    const int fq   = lane >> 4;

    const int nbx = N / BN;
    int bid = blockIdx.x;
    const int cpx = gridDim.x >> 3;
    bid = (bid & 7) * cpx + (bid >> 3);
    const int bx = bid % nbx, by = bid / nbx;
    const int m0 = by * BM, n0 = bx * BN;

    const int srow = tid / (BK / 8);
    const int sch  = tid & (BK / 8 - 1);
    const int ssw  = (BK == 64) ? (srow & 7) : ((srow >> 1) & 3);
    const int scs  = (sch ^ ssw) << 3;
    const unsigned short* gA = A  + (size_t)(m0 + srow) * K + scs;
    const unsigned short* gB = Bt + (size_t)(n0 + srow) * K + scs;

    const int frsw = (BK == 64) ? (fr & 7) : ((fr >> 1) & 3);

    f32x4_t acc[AF][BF];
    #pragma unroll
    for (int m = 0; m < AF; m++)
        #pragma unroll
        for (int n = 0; n < BF; n++)
            acc[m][n] = (f32x4_t){0.f, 0.f, 0.f, 0.f};

    const int NT = K / BK;

    auto STAGE = [&](int T) {
        const int pb = (T % NBUF) * BUF;
        #pragma unroll
        for (int q = 0; q < AR; ++q)
            gload_lds16(gA + (size_t)(q * ROWS) * K + (size_t)T * BK,
                        &smem[pb + q * 4096 + tid * 8]);
        #pragma unroll
        for (int q = 0; q < BR; ++q)
            gload_lds16(gB + (size_t)(q * ROWS) * K + (size_t)T * BK,
                        &smem[pb + BM * BK + q * 4096 + tid * 8]);
    };

    #pragma unroll
    for (int pt = 0; pt < NBUF - 1; ++pt) STAGE(pt);
    vmcnt_wait<DEPTH * RNDS>();

    for (int t = 0; t < NT; ++t) {
        const int sb = (t % NBUF) * BUF;
        BARF();   // the ONLY barrier per tile

        #pragma unroll
        for (int kk = 0; kk < KK; ++kk) {
            const int cxk = (((kk * 4 + fq) ^ frsw)) << 3;
            bf16x8_t aF[AF], bF[BF];
            #pragma unroll
            for (int mm = 0; mm < AF; ++mm)
                aF[mm] = *(const bf16x8_t*)&smem[sb + (wm*WM + mm*16 + fr)*BK + cxk];
            #pragma unroll
            for (int nn = 0; nn < BF; ++nn)
                bF[nn] = *(const bf16x8_t*)&smem[sb + BM*BK + (wn*WN + nn*16 + fr)*BK + cxk];

            if (kk == 0 && t + NBUF - 1 < NT) STAGE(t + NBUF - 1);

            __builtin_amdgcn_s_setprio(1);
            #pragma unroll
            for (int mm = 0; mm < AF; ++mm)
                #pragma unroll
                for (int nn = 0; nn < BF; ++nn)
                    acc[mm][nn] = __builtin_amdgcn_mfma_f32_16x16x32_bf16(
                        aF[mm], bF[nn], acc[mm][nn], 0, 0, 0);
            __builtin_amdgcn_s_setprio(0);
        }

        if constexpr (DEPTH == 2) {
            if (t + 3 < NT)      { vmcnt_wait<2 * RNDS>(); }
            else if (t + 2 < NT) { vmcnt_wait<RNDS>(); }
            else if (t + 1 < NT) { vmcnt_wait<0>(); }
        } else {
            if (t + 2 < NT)      { vmcnt_wait<RNDS>(); }
            else if (t + 1 < NT) { vmcnt_wait<0>(); }
        }
    }

    // C/D layout (m89-verified): col = lane&15, row = (lane>>4)*4 + reg
    const int crow = m0 + wm * WM + fq * 4;
    const int ccol = n0 + wn * WN + fr;
    #pragma unroll
    for (int m = 0; m < AF; m++)
        #pragma unroll
        for (int n = 0; n < BF; n++)
            #pragma unroll
            for (int rr = 0; rr < 4; rr++) {
                const size_t idx = (size_t)(crow + m*16 + rr) * N + ccol + n*16;
                if constexpr (OBF16) C[idx] = (OutT)f2b(acc[m][n][rr]);
                else                 C[idx] = (OutT)acc[m][n][rr];
            }
}

// ===========================================================================
// GEMM2: m201-style 8-phase schedule + coalesced LDS-transpose epilogue
// (round-16 measured best for this op).
// ===========================================================================
#define G2_BUF 32768   // shorts per buffer (64 KiB)

__global__ __launch_bounds__(512, 2)
void gemm2_8p(const unsigned short* __restrict__ A,
              const unsigned short* __restrict__ Bt,
              float* __restrict__ C) {
    constexpr int K     = O_N;        // 1024
    constexpr int N     = HID;        // 4096
    constexpr int NT    = K / 64;     // 16
    constexpr int NITER = NT / 2;     // 8

    __shared__ unsigned short smem[2 * G2_BUF];   // 128 KiB

    const int tid  = threadIdx.x;
    const int lane = tid & 63;
    const int wave = tid >> 6;
    const int wm   = wave >> 2;       // 0..1  (128 rows)
    const int wn   = wave & 3;        // 0..3  (64 cols)
    const int fr   = lane & 15;
    const int fq   = lane >> 4;

    const int nbx = N >> 8;           // 16
    int bid = blockIdx.x;
    const int cpx = gridDim.x >> 3;
    bid = (bid & 7) * cpx + (bid >> 3);
    const int bx = bid % nbx, by = bid / nbx;
    const int m0 = by << 8, n0 = bx << 8;

    const int srow = tid >> 3;
    const int scs  = ((tid & 7) ^ (srow & 7)) << 3;
    const unsigned short* gA = A  + (size_t)(m0 + srow) * K + scs;
    const unsigned short* gB = Bt + (size_t)(n0 + srow) * K + scs;
    const int frsw = fr & 7;

    f32x4_t acc[8][4];
    #pragma unroll
    for (int m = 0; m < 8; m++)
        #pragma unroll
        for (int n = 0; n < 4; n++)
            acc[m][n] = (f32x4_t){0.f, 0.f, 0.f, 0.f};

#define SA(T, q) gload_lds16(gA + (size_t)((q)*64)*K + (size_t)(T)*64, \
                             &smem[((T)&1)*G2_BUF + (q)*4096 + tid*8])
#define SB(T, q) gload_lds16(gB + (size_t)((q)*64)*K + (size_t)(T)*64, \
                             &smem[((T)&1)*G2_BUF + 16384 + (q)*4096 + tid*8])
#define RDA(T, MH, KI) { _Pragma("unroll") for (int mm = 0; mm < 4; ++mm) { \
    const int ro = ((T)&1)*G2_BUF + (wm*128 + (MH)*64 + mm*16 + fr)*64; \
    aF[mm] = *(const bf16x8_t*)&smem[ro + ((((KI)*4 + fq) ^ frsw) << 3)]; } }
#define RDB(T, KI, dst) { _Pragma("unroll") for (int nn = 0; nn < 4; ++nn) { \
    const int ro = ((T)&1)*G2_BUF + 16384 + (wn*64 + nn*16 + fr)*64; \
    dst[nn] = *(const bf16x8_t*)&smem[ro + ((((KI)*4 + fq) ^ frsw) << 3)]; } }
#define MM16(MH, BS) { __builtin_amdgcn_s_setprio(1); \
    _Pragma("unroll") for (int mm = 0; mm < 4; ++mm) \
    _Pragma("unroll") for (int nn = 0; nn < 4; ++nn) \
        acc[(MH)*4 + mm][nn] = __builtin_amdgcn_mfma_f32_16x16x32_bf16( \
            aF[mm], BS[nn], acc[(MH)*4 + mm][nn], 0, 0, 0); \
    __builtin_amdgcn_s_setprio(0); }

    SA(0,0); SA(0,1); SA(0,2); SA(0,3);
    SB(0,0); SB(0,1); SB(0,2); SB(0,3);
    SA(1,0); SA(1,2); SB(1,0); SB(1,1);
    vmcnt_wait<4>();
    BARF();

    for (int i = 0; i < NITER; ++i) {
        const int t0 = 2*i, t1 = 2*i + 1;
        bf16x8_t aF[4], b0[4], b1[4];

        RDA(t0, 0, 0); RDB(t0, 0, b0);
        SA(t1, 1); SA(t1, 3);
        BARF(); LGKMW(); MM16(0, b0); BARF();

        RDA(t0, 0, 1); RDB(t0, 1, b1);
        SB(t1, 2); SB(t1, 3);
        BARF(); LGKMW(); MM16(0, b1); BARF();

        RDA(t0, 1, 0);
        if (t0 + 2 < NT) { SA(t0 + 2, 0); SA(t0 + 2, 2); }
        BARF(); LGKMW(); MM16(1, b0); BARF();

        RDA(t0, 1, 1);
        if (t0 + 2 < NT) { SB(t0 + 2, 0); SB(t0 + 2, 1); }
        BARF(); LGKMW(); MM16(1, b1);
        if (i + 1 < NITER) { vmcnt_wait<4>(); } else { vmcnt_wait<0>(); }
        BARF();

        RDA(t1, 0, 0); RDB(t1, 0, b0);
        if (t0 + 2 < NT) { SA(t0 + 2, 1); SA(t0 + 2, 3); }
        BARF(); LGKMW(); MM16(0, b0); BARF();

        RDA(t1, 0, 1); RDB(t1, 1, b1);
        if (t0 + 2 < NT) { SB(t0 + 2, 2); SB(t0 + 2, 3); }
        BARF(); LGKMW(); MM16(0, b1); BARF();

        RDA(t1, 1, 0);
        if (t1 + 2 < NT) { SA(t1 + 2, 0); SA(t1 + 2, 2); }
        BARF(); LGKMW(); MM16(1, b0); BARF();

        RDA(t1, 1, 1);
        if (t1 + 2 < NT) { SB(t1 + 2, 0); SB(t1 + 2, 1); }
        BARF(); LGKMW(); MM16(1, b1);
        if (i + 1 < NITER) { vmcnt_wait<4>(); }
        BARF();
    }
#undef SA
#undef SB
#undef RDA
#undef RDB
#undef MM16

    // ---- coalesced epilogue: LDS-transpose to 1KB-contiguous float4 stores
    float* lf = (float*)smem;
    for (int h = 0; h < 2; ++h) {
        BARF();   // h=0: after K-loop; h=1: pass-0 reads done before overwrite
        if (wm == h) {
            #pragma unroll
            for (int m = 0; m < 8; m++)
                #pragma unroll
                for (int n = 0; n < 4; n++)
                    #pragma unroll
                    for (int rr = 0; rr < 4; rr++) {
                        const int row = m*16 + fq*4 + rr;
                        const int col = wn*64 + n*16 + fr;
                        lf[row*256 + (col ^ ((row & 7) << 2))] = acc[m][n][rr];
                    }
        }
        BARF();
        #pragma unroll
        for (int i = 0; i < 16; i++) {
            const int row = wave*16 + i;
            const int sw  = (row & 7) << 2;
            const float4 v = *(const float4*)&lf[row*256 + ((lane*4) ^ sw)];
            *(float4*)&C[(size_t)(m0 + h*128 + row) * N + n0 + lane*4] = v;
        }
    }
}

// --------- fused RMSNorm + RoPE + 16-token block-diagonal attention --------
__global__ __launch_bounds__(64) void attn_fused(const unsigned short* __restrict__ qkv,
                                                 const float* __restrict__ cosb,
                                                 const float* __restrict__ sinb,
                                                 const float* __restrict__ qw,
                                                 const float* __restrict__ kw,
                                                 unsigned short* __restrict__ out) {
    const int h    = blockIdx.x & (NH - 1);
    const int blk  = (blockIdx.x >> 4) & 127;
    const int b    = blockIdx.x >> 11;
    const int pos0 = blk * 16;
    const int kvh  = h >> 2;

    const int lane = threadIdx.x;
    const int r    = lane >> 2;
    const int qp   = lane & 3;
    const int d0   = qp * 16;

    __shared__ float qs[16][65];
    __shared__ float ks[16][65];
    __shared__ float vs[16][65];
    __shared__ float ps[16][17];

    const size_t rowb = ((size_t)(b * L_SEQ + pos0 + r)) * NQKV;
    const unsigned short* qptr = qkv + (rowb + h) * HD + d0;
    const unsigned short* kptr = qkv + (rowb + NH + kvh) * HD + d0;
    const unsigned short* vptr = qkv + (rowb + NH + NKV + kvh) * HD + d0;
    const size_t csrow = ((size_t)(b * L_SEQ + pos0 + r)) * HD + d0;

    float q[16], k[16], v[16], cs[16], sn[16];
    {
        ushort8_t q0 = *(const ushort8_t*)&qptr[0], q1 = *(const ushort8_t*)&qptr[8];
        ushort8_t k0 = *(const ushort8_t*)&kptr[0], k1 = *(const ushort8_t*)&kptr[8];
        ushort8_t v0 = *(const ushort8_t*)&vptr[0], v1 = *(const ushort8_t*)&vptr[8];
        #pragma unroll
        for (int i = 0; i < 8; i++) {
            q[i] = b2f(q0[i]); q[i+8] = b2f(q1[i]);
            k[i] = b2f(k0[i]); k[i+8] = b2f(k1[i]);
            v[i] = b2f(v0[i]); v[i+8] = b2f(v1[i]);
        }
        #pragma unroll
        for (int i = 0; i < 16; i += 4) {
            *(float4*)&cs[i] = *(const float4*)&cosb[csrow + i];
            *(float4*)&sn[i] = *(const float4*)&sinb[csrow + i];
        }
    }

    float sq = 0.f, sk = 0.f;
    #pragma unroll
    for (int i = 0; i < 16; i++) { sq += q[i]*q[i]; sk += k[i]*k[i]; }
    sq += __shfl_xor(sq, 1); sq += __shfl_xor(sq, 2);
    sk += __shfl_xor(sk, 1); sk += __shfl_xor(sk, 2);
    const float rq = rsqrtf(sq * (1.f / HD) + EPSV);
    const float rk = rsqrtf(sk * (1.f / HD) + EPSV);

    const float sgn = (qp < 2) ? -1.f : 1.f;
    #pragma unroll
    for (int i = 0; i < 16; i++) {
        float qn = q[i] * rq * qw[d0 + i];
        float kn = k[i] * rk * kw[d0 + i];
        float qo = __shfl_xor(qn, 2);
        float ko = __shfl_xor(kn, 2);
        qs[r][d0 + i] = qn * cs[i] + sgn * qo * sn[i];
        ks[r][d0 + i] = kn * cs[i] + sgn * ko * sn[i];
        vs[r][d0 + i] = v[i];
    }
    __syncthreads();

    float sc[4] = {0.f, 0.f, 0.f, 0.f};
    for (int d = 0; d < 64; d++) {
        const float qd = qs[r][d];
        sc[0] += qd * ks[qp     ][d];
        sc[1] += qd * ks[qp +  4][d];
        sc[2] += qd * ks[qp +  8][d];
        sc[3] += qd * ks[qp + 12][d];
    }
    #pragma unroll
    for (int cc = 0; cc < 4; cc++) {
        const int c = qp + cc * 4;
        sc[cc] = (c <= r) ? sc[cc] * 0.125f : -3.0e38f;
    }
    float mx = fmaxf(fmaxf(sc[0], sc[1]), fmaxf(sc[2], sc[3]));
    mx = fmaxf(mx, __shfl_xor(mx, 1));
    mx = fmaxf(mx, __shfl_xor(mx, 2));
    float e[4], sum = 0.f;
    #pragma unroll
    for (int cc = 0; cc < 4; cc++) { e[cc] = __expf(sc[cc] - mx); sum += e[cc]; }
    sum += __shfl_xor(sum, 1); sum += __shfl_xor(sum, 2);
    const float inv = 1.f / sum;
    #pragma unroll
    for (int cc = 0; cc < 4; cc++) ps[r][qp + cc * 4] = e[cc] * inv;
    __syncthreads();

    float o[16];
    #pragma unroll
    for (int i = 0; i < 16; i++) o[i] = 0.f;
    #pragma unroll
    for (int c = 0; c < 16; c++) {
        const float p = ps[r][c];
        #pragma unroll
        for (int i = 0; i < 16; i++) o[i] += p * vs[c][d0 + i];
    }

    __attribute__((aligned(16))) unsigned short ob[16];
    #pragma unroll
    for (int i = 0; i < 16; i++) ob[i] = f2b(o[i]);
    unsigned short* optr = out + (((size_t)(b * L_SEQ + pos0 + r) * NH + h) * HD) + d0;
    *(uint4*)optr       = *(uint4*)&ob[0];
    *((uint4*)optr + 1) = *(uint4*)&ob[8];
}

// ---------------------------------------------------------------------------
extern "C" void kernel_launch(void* const* d_in, const int* in_sizes, int n_in,
                              void* d_out, int out_size, void* d_ws, size_t ws_size,
                              hipStream_t stream) {
    const float* hid  = (const float*)d_in[0];
    const float* cosb = (const float*)d_in[2];
    const float* sinb = (const float*)d_in[3];
    const float* Wqkv = (const float*)d_in[4];
    const float* Wo   = (const float*)d_in[5];
    const float* qw   = (const float*)d_in[6];
    const float* kw   = (const float*)d_in[7];
    float* outp = (float*)d_out;

    char* ws = (char*)d_ws;
    unsigned short* Hb    = (unsigned short*)ws; ws += (size_t)M_ROWS * HID * 2;
    unsigned short* WqkvT = (unsigned short*)ws; ws += (size_t)QKV_N * HID * 2;
    unsigned short* WoT   = (unsigned short*)ws; ws += (size_t)HID * O_N * 2;
    unsigned short* qkvb  = (unsigned short*)ws; ws += (size_t)M_ROWS * QKV_N * 2;
    unsigned short* attnb = (unsigned short*)ws;

    // prep: cvt + both transposes in ONE launch
    prep<<<dim3(CVT_BLKS + 6144 + 4096), 256, 0, stream>>>
        (hid, Hb, Wqkv, WqkvT, Wo, WoT);

    // GEMM1 (measured best): 128x192, BK=64, NBUF=3, 256 blocks
    gemm_sb<128, 192, 64, 3, 2, 4, true, unsigned short>
        <<<dim3((M_ROWS / 128) * (QKV_N / 192)), 512, 0, stream>>>
        (Hb, WqkvT, qkvb, M_ROWS, QKV_N, HID);

    // fused rmsnorm + rope + block-diag attention (bf16 in/out)
    attn_fused<<<dim3(B_SZ * (L_SEQ / 16) * NH), 64, 0, stream>>>(qkvb, cosb, sinb, qw, kw, attnb);

    // GEMM2 (measured best): 8-phase 256^2 + coalesced LDS-transpose epilogue
    gemm2_8p<<<dim3((M_ROWS / 256) * (HID / 256)), 512, 0, stream>>>
        (attnb, WoT, outp);
}